// Round 25
// baseline (622.602 us; speedup 1.0000x reference)
//
#include <hip/hip_runtime.h>
#include <math.h>

// B=4, DIM=192, H=W=64, L=4096, HEADS=6. f32 buffers; f64 routing chain (b=0).
// Dense experts AND ex_out via bf16 MFMA 32x32x16 GEMM-conv, LDS-staged rows.
// Each wave: one mt (32 oc) x full 64-px row; av shared across both nt halves
// (halves A/L2 traffic); each nt acc split even/odd ks -> 4 indep MFMA chains.
// Depthwise expert: ch-coalesced, transposed weights in registers, 4 px/block.
// Routing tail collapsed by linearity (exact in f64).

struct ExPtrs { const float* w[12]; const float* b[12]; };
struct BfPtrs { const short* adt[6]; const float* bias[6]; };

typedef __attribute__((ext_vector_type(8))) short short8v;
typedef __attribute__((ext_vector_type(4))) short short4v;
typedef __attribute__((ext_vector_type(16))) float f32x16;

__device__ __forceinline__ void fma4(float4& a, float s, const float4& v) {
    a.x = fmaf(s, v.x, a.x); a.y = fmaf(s, v.y, a.y);
    a.z = fmaf(s, v.z, a.z); a.w = fmaf(s, v.w, a.w);
}

__device__ __forceinline__ short f2bf(float v) {
    unsigned u = __float_as_uint(v);
    return (short)((u + 0x7FFFu + ((u >> 16) & 1u)) >> 16);
}

__device__ __forceinline__ float bf2f(short v) {
    return __uint_as_float(((unsigned)(unsigned short)v) << 16);
}

// ---------------- helpers ----------------
__global__ void zero_kernel(float* __restrict__ p, int n) {
    for (int i = blockIdx.x * 256 + threadIdx.x; i < n; i += gridDim.x * 256) p[i] = 0.f;
}

__global__ void packIbf_kernel(const float* __restrict__ I, short* __restrict__ Ibf) {
    const int n = 4 * 68 * 68 * 192;
    for (int o = blockIdx.x * 256 + threadIdx.x; o < n; o += gridDim.x * 256) {
        int ch = o % 192;
        int t = o / 192;
        int xx = t % 68; t /= 68;
        int yy = t % 68;
        int b = t / 68;
        short v = 0;
        if (yy >= 2 && yy < 66 && xx >= 2 && xx < 66)
            v = f2bf(I[(((size_t)(b * 192 + ch)) << 12) + (yy - 2) * 64 + (xx - 2)]);
        Ibf[o] = v;
    }
}

// dense expert j weights [192][192][K][K] -> bf16 [tap][mt(6)][ks(12)][lane(64)][8]
__global__ void packAd_kernel(const float* __restrict__ w, short* __restrict__ Ad, int K2) {
    int n = K2 * 6 * 12 * 64 * 8;
    for (int o = blockIdx.x * 256 + threadIdx.x; o < n; o += gridDim.x * 256) {
        int j = o & 7;
        int t = o >> 3;
        int l = t & 63; t >>= 6;
        int ks = t % 12; t /= 12;
        int mt = t % 6;
        int tap = t / 6;
        int oc = mt * 32 + (l & 31);
        int ic = ks * 16 + (l >> 5) * 8 + j;
        Ad[o] = f2bf(w[(((size_t)oc * 192) + ic) * K2 + tap]);
    }
}

// exow [192][768][3][3] -> At bf16 [tap][mt(6)][ksg(48)][lane(64)][8]
__global__ void packA_kernel(const float* __restrict__ exow, short* __restrict__ At) {
    const int n = 9 * 6 * 48 * 64 * 8;
    for (int o = blockIdx.x * 256 + threadIdx.x; o < n; o += gridDim.x * 256) {
        int j = o & 7;
        int t = o >> 3;
        int l = t & 63; t >>= 6;
        int ks = t % 48; t /= 48;
        int mt = t % 6;
        int tap = t / 6;
        int oc = mt * 32 + (l & 31);
        int icg = ks * 16 + (l >> 5) * 8 + j;
        At[o] = f2bf(exow[((size_t)oc * 768 + icg) * 9 + tap]);
    }
}

__global__ void wtr8_kernel(const float* __restrict__ w, float* __restrict__ wt,
                            int OCg, int IC, int K2) {
    int n = OCg * IC * K2 * 8;
    for (int o = blockIdx.x * 256 + threadIdx.x; o < n; o += gridDim.x * 256) {
        int u = o & 7;
        int t = o >> 3;
        int kk = t % K2;
        int t2 = t / K2;
        int ic = t2 % IC;
        int og = t2 / IC;
        wt[o] = w[(((size_t)(og * 8 + u)) * IC + ic) * K2 + kk];
    }
}

// dw experts (j=6..11): wdwt[e][kk][ch] = w_j[ch*K2+kk]. 6*25*192 entries.
__global__ void packWdw_kernel(ExPtrs ep, float* __restrict__ wdwt) {
    int o = blockIdx.x * 256 + threadIdx.x;
    if (o >= 6 * 25 * 192) return;
    int ch = o % 192;
    int t = o / 192;
    int kk = t % 25;
    int e = t / 25;
    int j = e + 6;
    int K = 1 + 2 * (j % 3);
    int K2 = K * K;
    wdwt[o] = (kk < K2) ? ep.w[j][(size_t)ch * K2 + kk] : 0.f;
}

// ================= routing chain, b=0, all f64 =================

__global__ void pool64_kernel(const float* __restrict__ T, double* __restrict__ xp) {
    int j = blockIdx.x;
    for (int l = threadIdx.x; l < 4096; l += 256) {
        const float* t = T + ((size_t)(4 * j)) * 4096 + l;
        double s = (double)t[0] + (double)t[4096] + (double)t[2 * 4096] + (double)t[3 * 4096];
        xp[(size_t)j * 4096 + l] = 0.25 * s;
    }
}

__global__ void norm64_f32_kernel(const float* __restrict__ src, double* __restrict__ dst) {
    size_t off = (size_t)blockIdx.x * 4096;
    double acc = 0.0;
    for (int i = threadIdx.x; i < 4096; i += 256) { double v = src[off + i]; acc += v * v; }
    __shared__ double red[256];
    red[threadIdx.x] = acc; __syncthreads();
    for (int st = 128; st > 0; st >>= 1) {
        if (threadIdx.x < st) red[threadIdx.x] += red[threadIdx.x + st];
        __syncthreads();
    }
    double scale = 1.0 / fmax(sqrt(red[0]), 1e-12);
    for (int i = threadIdx.x; i < 4096; i += 256) dst[off + i] = src[off + i] * scale;
}

__global__ void norm64_f64_kernel(double* __restrict__ buf) {
    size_t off = (size_t)blockIdx.x * 4096;
    double acc = 0.0;
    for (int i = threadIdx.x; i < 4096; i += 256) { double v = buf[off + i]; acc += v * v; }
    __shared__ double red[256];
    red[threadIdx.x] = acc; __syncthreads();
    for (int st = 128; st > 0; st >>= 1) {
        if (threadIdx.x < st) red[threadIdx.x] += red[threadIdx.x + st];
        __syncthreads();
    }
    double scale = 1.0 / fmax(sqrt(red[0]), 1e-12);
    for (int i = threadIdx.x; i < 4096; i += 256) buf[off + i] *= scale;
}

__global__ void attnA64p_kernel(const double* __restrict__ qn, const double* __restrict__ kn,
                                double* __restrict__ PA) {
    int hh = blockIdx.x, cc = blockIdx.y;
    int t = threadIdx.x;
    int c = t >> 3, d = t & 7;
    const double* q = qn + ((size_t)(hh * 32 + c)) * 4096 + cc * 256;
    const double* k = kn + ((size_t)(hh * 8 + d)) * 4096 + cc * 256;
    double acc = 0.0;
    for (int i = 0; i < 256; ++i) acc += q[i] * k[i];
    PA[((size_t)((hh * 32 + c) * 8 + d)) * 16 + cc] = acc;
}

__global__ void attnA64r_kernel(const double* __restrict__ PA, double* __restrict__ A) {
    int hh = blockIdx.x;
    int t = threadIdx.x;
    int c = t >> 3, d = t & 7;
    double acc = 0.0;
    const double* p = PA + ((size_t)((hh * 32 + c) * 8 + d)) * 16;
    for (int cc = 0; cc < 16; ++cc) acc += p[cc];
    __shared__ double S[32][8];
    S[c][d] = acc;
    __syncthreads();
    if (t < 32) {
        double mx = -1e300;
        for (int j = 0; j < 8; ++j) mx = fmax(mx, S[t][j]);
        double e[8], sum = 0.0;
        for (int j = 0; j < 8; ++j) { e[j] = exp(S[t][j] - mx); sum += e[j]; }
        double inv = 1.0 / sum;
        for (int j = 0; j < 8; ++j) A[((size_t)(hh * 32 + t)) * 8 + j] = e[j] * inv;
    }
}

// kcol[j][x] = sum_y kn[j][y*64+x], j<48. grid (48), 64 thr.
__global__ void kcol64_kernel(const double* __restrict__ kn, double* __restrict__ kcol) {
    int j = blockIdx.x, x = threadIdx.x;
    const double* s = kn + (size_t)j * 4096 + x;
    double acc = 0.0;
    for (int y = 0; y < 64; ++y) acc += s[y * 64];
    kcol[j * 64 + x] = acc;
}

// wsum[ic] = sum_oc ca1[oc*192+ic]. grid (1), 192 thr.
__global__ void wsum64_kernel(const float* __restrict__ ca1, double* __restrict__ wsum) {
    int ic = threadIdx.x;
    if (ic >= 192) return;
    double acc = 0.0;
    for (int oc = 0; oc < 192; ++oc) acc += (double)ca1[(size_t)oc * 192 + ic];
    wsum[ic] = acc;
}

// m[x] = (1/12288) sum_ic wsum[ic] * sum_d A[ic*8+d]*kcol[(ic>>5)*8+d][x]. grid (1), 64 thr.
__global__ void mroute64_kernel(const double* __restrict__ A, const double* __restrict__ kcol,
                                const double* __restrict__ wsum, double* __restrict__ m) {
    int x = threadIdx.x;
    if (x >= 64) return;
    double acc = 0.0;
    for (int ic = 0; ic < 192; ++ic) {
        int hh = ic >> 5;
        double s = 0.0;
        #pragma unroll
        for (int d = 0; d < 8; ++d)
            s += A[(size_t)ic * 8 + d] * kcol[(hh * 8 + d) * 64 + x];
        acc += wsum[ic] * s;
    }
    m[x] = acc / (192.0 * 64.0);
}

__global__ void route64_kernel(const double* __restrict__ m, int* __restrict__ idx) {
    if (threadIdx.x != 0) return;
    double bins[12];
    for (int i = 0; i < 12; ++i) {
        int st = (i * 64) / 12;
        int en = ((i + 1) * 64 + 11) / 12;   // ceil
        double s = 0.0;
        for (int j = st; j < en; ++j) s += m[j];
        bins[i] = s / (double)(en - st);
    }
    bool used[12] = {};
    for (int s = 0; s < 4; ++s) {
        int best = 0; double bv = -1e300;
        for (int j = 0; j < 12; ++j)
            if (!used[j] && bins[j] > bv) { best = j; bv = bins[j]; }
        used[best] = true;
        idx[s] = best;
    }
}

// ================= f32 compute kernels =================

__global__ void rownorm_kernel(const float* __restrict__ src, float* __restrict__ dst) {
    size_t off = (size_t)blockIdx.x * 4096;
    const float* s = src + off;
    float acc = 0.f;
    for (int i = threadIdx.x; i < 4096; i += 256) { float v = s[i]; acc += v * v; }
    __shared__ float red[256];
    red[threadIdx.x] = acc; __syncthreads();
    for (int st = 128; st > 0; st >>= 1) {
        if (threadIdx.x < st) red[threadIdx.x] += red[threadIdx.x + st];
        __syncthreads();
    }
    float scale = 1.0f / fmaxf(sqrtf(red[0]), 1e-12f);
    float* d = dst + off;
    for (int i = threadIdx.x; i < 4096; i += 256) d[i] = s[i] * scale;
}

// ---- dense expert via 32x32x16 MFMA; wave = (mt, full 64-px row). ----
// Block: 3 waves (192 thr), grid (64, 2, 4); mt = by*3 + wave in [0,6).
// av shared across nt halves; each nt acc split even/odd ks (4 indep chains).
template<int KK>
__device__ __forceinline__ void dmf_body(const short* __restrict__ Ad,
                                         const short* __restrict__ Ibf,
                                         const float* __restrict__ bias,
                                         short* __restrict__ Ebf, int cslot,
                                         int b, int y, short* __restrict__ sb) {
    constexpr int P = (KK - 1) / 2;
    int tid = threadIdx.x;
    int lane = tid & 63, wave = tid >> 6;       // wave 0..2
    int mt = blockIdx.y * 3 + wave;             // 0..5
    int c32 = lane & 31, hi = lane >> 5;
    f32x16 a0e, a0o, a1e, a1o;
    #pragma unroll
    for (int r = 0; r < 16; ++r) {
        float bv_ = bias[mt * 32 + (r & 3) + 8 * (r >> 2) + 4 * hi];
        a0e[r] = bv_; a1e[r] = bv_; a0o[r] = 0.f; a1o[r] = 0.f;
    }
    for (int rr = 0; rr < KK; ++rr) {
        const short* src = Ibf + ((size_t)(b * 68 + y + 2 - P + rr)) * 68 * 192;
        if (rr > 0) __syncthreads();
        for (int g2 = tid; g2 < 68 * 24; g2 += 192) {
            int px = g2 / 24, ck = g2 % 24;
            *(short8v*)(sb + px * 200 + ck * 8) = *(const short8v*)(src + px * 192 + ck * 8);
        }
        __syncthreads();
        for (int dx = 0; dx < KK; ++dx) {
            int tap = rr * KK + dx;
            const short* Ab = Ad + (((size_t)(tap * 6 + mt)) * 12) * 512 + (size_t)lane * 8;
            const short* Bb0 = sb + ((2 - P) + dx + c32) * 200 + hi * 8;
            const short* Bb1 = Bb0 + 32 * 200;
            #pragma unroll 2
            for (int k2 = 0; k2 < 6; ++k2) {
                short8v ave = *(const short8v*)(Ab + (2 * k2) * 512);
                short8v avo = *(const short8v*)(Ab + (2 * k2 + 1) * 512);
                short8v b0e = *(const short8v*)(Bb0 + (2 * k2) * 16);
                short8v b0o = *(const short8v*)(Bb0 + (2 * k2 + 1) * 16);
                short8v b1e = *(const short8v*)(Bb1 + (2 * k2) * 16);
                short8v b1o = *(const short8v*)(Bb1 + (2 * k2 + 1) * 16);
                a0e = __builtin_amdgcn_mfma_f32_32x32x16_bf16(ave, b0e, a0e, 0, 0, 0);
                a1e = __builtin_amdgcn_mfma_f32_32x32x16_bf16(ave, b1e, a1e, 0, 0, 0);
                a0o = __builtin_amdgcn_mfma_f32_32x32x16_bf16(avo, b0o, a0o, 0, 0, 0);
                a1o = __builtin_amdgcn_mfma_f32_32x32x16_bf16(avo, b1o, a1o, 0, 0, 0);
            }
        }
    }
    short* db0 = Ebf + (((size_t)(b * 66 + y + 1)) * 68 + (c32 + 1)) * 384
                 + cslot * 192 + mt * 32 + 4 * hi;
    short* db1 = Ebf + (((size_t)(b * 66 + y + 1)) * 68 + (32 + c32 + 1)) * 384
                 + cslot * 192 + mt * 32 + 4 * hi;
    #pragma unroll
    for (int g = 0; g < 4; ++g) {
        short4v o0, o1;
        #pragma unroll
        for (int r = 0; r < 4; ++r) {
            o0[r] = f2bf(a0e[g * 4 + r] + a0o[g * 4 + r]);
            o1[r] = f2bf(a1e[g * 4 + r] + a1o[g * 4 + r]);
        }
        *(short4v*)(db0 + g * 8) = o0;
        *(short4v*)(db1 + g * 8) = o1;
    }
}

// grid (64, 2, 4), 192 thr.
__global__ void dense_mfma_kernel(BfPtrs bp, const short* __restrict__ Ibf,
                                  const int* __restrict__ idx, int slot,
                                  short* __restrict__ Ebf, int cslot) {
    __shared__ short sb[68 * 200];
    int j = idx[slot];
    j = j < 0 ? 0 : (j > 11 ? 11 : j);
    if (j >= 6) return;
    int y = blockIdx.x, b = blockIdx.z;
    int m = j % 3;
    if (m == 0) dmf_body<1>(bp.adt[j], Ibf, bp.bias[j], Ebf, cslot, b, y, sb);
    else if (m == 1) dmf_body<3>(bp.adt[j], Ibf, bp.bias[j], Ebf, cslot, b, y, sb);
    else dmf_body<5>(bp.adt[j], Ibf, bp.bias[j], Ebf, cslot, b, y, sb);
}

// ---- depthwise body: ch-coalesced, weights in registers, 4 px/block ----
template<int KK>
__device__ __forceinline__ void dw_body(const short* __restrict__ Ibf,
                                        const float* __restrict__ wt,
                                        float bias,
                                        short* __restrict__ Ebf, int cslot,
                                        int b, int pg, int ch) {
    constexpr int P = (KK - 1) / 2;
    constexpr int K2 = KK * KK;
    float wreg[K2];
    #pragma unroll
    for (int kk = 0; kk < K2; ++kk) wreg[kk] = wt[kk * 192 + ch];
    #pragma unroll
    for (int u = 0; u < 4; ++u) {
        int px = pg * 4 + u;
        int y = px >> 6, x = px & 63;
        const short* base = Ibf + ((size_t)(b * 68 + y + 2 - P)) * 68 * 192
                            + (size_t)(x + 2 - P) * 192 + ch;
        float acc = bias;
        #pragma unroll
        for (int ky = 0; ky < KK; ++ky)
            #pragma unroll
            for (int kx = 0; kx < KK; ++kx)
                acc = fmaf(wreg[ky * KK + kx], bf2f(base[(ky * 68 + kx) * 192]), acc);
        Ebf[(((size_t)(b * 66 + y + 1)) * 68 + (x + 1)) * 384 + cslot * 192 + ch] = f2bf(acc);
    }
}

// grid (1024, 4), 192 thr.
__global__ void dw_bf_kernel(const short* __restrict__ Ibf, const float* __restrict__ wdwt,
                             ExPtrs ep, const int* __restrict__ idx, int slot,
                             short* __restrict__ Ebf, int cslot) {
    int j = idx[slot];
    j = j < 0 ? 0 : (j > 11 ? 11 : j);
    if (j < 6) return;
    int ch = threadIdx.x;
    int pg = blockIdx.x, b = blockIdx.y;
    const float* wt = wdwt + (size_t)(j - 6) * 25 * 192;
    float bias = ep.b[j][ch];
    int m = j % 3;
    if (m == 0) dw_body<1>(Ibf, wt, bias, Ebf, cslot, b, pg, ch);
    else if (m == 1) dw_body<3>(Ibf, wt, bias, Ebf, cslot, b, pg, ch);
    else dw_body<5>(Ibf, wt, bias, Ebf, cslot, b, pg, ch);
}

// ex_out via 32x32x16 MFMA, same wave decomposition. grid (64,2,4), 192 thr.
__global__ void exout_mfma_kernel(const short* __restrict__ At, const short* __restrict__ Ebf,
                                  const float* __restrict__ bias, float* __restrict__ out,
                                  int pass) {
    __shared__ short sb[68 * 392];
    int y = blockIdx.x, b = blockIdx.z;
    int tid = threadIdx.x;
    int lane = tid & 63, wave = tid >> 6;
    int mt = blockIdx.y * 3 + wave;
    int c32 = lane & 31, hi = lane >> 5;
    float* d0 = out + ((size_t)(b * 192 + mt * 32)) * 4096 + y * 64 + c32;
    float* d1 = d0 + 32;
    f32x16 a0e, a0o, a1e, a1o;
    if (pass == 0) {
        #pragma unroll
        for (int r = 0; r < 16; ++r) {
            float bv_ = bias[mt * 32 + (r & 3) + 8 * (r >> 2) + 4 * hi];
            a0e[r] = bv_; a1e[r] = bv_; a0o[r] = 0.f; a1o[r] = 0.f;
        }
    } else {
        #pragma unroll
        for (int r = 0; r < 16; ++r) {
            size_t ro = (size_t)((r & 3) + 8 * (r >> 2) + 4 * hi) * 4096;
            a0e[r] = d0[ro]; a1e[r] = d1[ro];
            a0o[r] = 0.f; a1o[r] = 0.f;
        }
    }
    for (int rr = 0; rr < 3; ++rr) {
        const short* src = Ebf + ((size_t)(b * 66 + y + rr)) * 68 * 384;
        if (rr > 0) __syncthreads();
        for (int g2 = tid; g2 < 68 * 48; g2 += 192) {
            int px = g2 / 48, ck = g2 % 48;
            *(short8v*)(sb + px * 392 + ck * 8) = *(const short8v*)(src + px * 384 + ck * 8);
        }
        __syncthreads();
        for (int dx = 0; dx < 3; ++dx) {
            int tap = rr * 3 + dx;
            const short* Ab = At + (((size_t)(tap * 6 + mt)) * 48 + pass * 24) * 512
                              + (size_t)lane * 8;
            const short* Bb0 = sb + (dx + c32) * 392 + hi * 8;
            const short* Bb1 = Bb0 + 32 * 392;
            #pragma unroll 2
            for (int k2 = 0; k2 < 12; ++k2) {
                short8v ave = *(const short8v*)(Ab + (size_t)(2 * k2) * 512);
                short8v avo = *(const short8v*)(Ab + (size_t)(2 * k2 + 1) * 512);
                short8v b0e = *(const short8v*)(Bb0 + (2 * k2) * 16);
                short8v b0o = *(const short8v*)(Bb0 + (2 * k2 + 1) * 16);
                short8v b1e = *(const short8v*)(Bb1 + (2 * k2) * 16);
                short8v b1o = *(const short8v*)(Bb1 + (2 * k2 + 1) * 16);
                a0e = __builtin_amdgcn_mfma_f32_32x32x16_bf16(ave, b0e, a0e, 0, 0, 0);
                a1e = __builtin_amdgcn_mfma_f32_32x32x16_bf16(ave, b1e, a1e, 0, 0, 0);
                a0o = __builtin_amdgcn_mfma_f32_32x32x16_bf16(avo, b0o, a0o, 0, 0, 0);
                a1o = __builtin_amdgcn_mfma_f32_32x32x16_bf16(avo, b1o, a1o, 0, 0, 0);
            }
        }
    }
    #pragma unroll
    for (int r = 0; r < 16; ++r) {
        size_t ro = (size_t)((r & 3) + 8 * (r >> 2) + 4 * hi) * 4096;
        d0[ro] = a0e[r] + a0o[r];
        d1[ro] = a1e[r] + a1o[r];
    }
}

// 1x1 conv, 8oc. grid (4, 24, 4). wt pre-offset for oc-half.
__global__ void conv1x1_sw_kernel(const float* __restrict__ in, const float* __restrict__ wtg,
                                  float* __restrict__ out) {
    int tid = threadIdx.x;
    int xq = tid & 15, ry = tid >> 4;
    int tile = blockIdx.x, og = blockIdx.y, b = blockIdx.z;
    int p0 = tile * 1024 + ry * 64 + xq * 4;
    float4 acc[8] = {};
    const float* src = in + (size_t)b * 192 * 4096 + p0;
    const float* wp = wtg + (size_t)og * 192 * 8;
    for (int ic = 0; ic < 192; ic += 2) {
        float4 xv0 = *(const float4*)(src + (size_t)ic * 4096);
        float4 xv1 = *(const float4*)(src + (size_t)(ic + 1) * 4096);
        float4 wA0 = *(const float4*)(wp + ic * 8);
        float4 wB0 = *(const float4*)(wp + ic * 8 + 4);
        float4 wA1 = *(const float4*)(wp + ic * 8 + 8);
        float4 wB1 = *(const float4*)(wp + ic * 8 + 12);
        fma4(acc[0], wA0.x, xv0); fma4(acc[1], wA0.y, xv0);
        fma4(acc[2], wA0.z, xv0); fma4(acc[3], wA0.w, xv0);
        fma4(acc[4], wB0.x, xv0); fma4(acc[5], wB0.y, xv0);
        fma4(acc[6], wB0.z, xv0); fma4(acc[7], wB0.w, xv0);
        fma4(acc[0], wA1.x, xv1); fma4(acc[1], wA1.y, xv1);
        fma4(acc[2], wA1.z, xv1); fma4(acc[3], wA1.w, xv1);
        fma4(acc[4], wB1.x, xv1); fma4(acc[5], wB1.y, xv1);
        fma4(acc[6], wB1.z, xv1); fma4(acc[7], wB1.w, xv1);
    }
    float* dst = out + ((size_t)(b * 192 + og * 8)) * 4096 + p0;
    #pragma unroll
    for (int u = 0; u < 8; ++u)
        *(float4*)(dst + (size_t)u * 4096) = acc[u];
}

// depthwise 3x3 pad1 no bias; plain in/out; w pre-offset. grid (16,192,4)
__global__ void dwconv_kernel(const float* __restrict__ in, const float* __restrict__ w,
                              float* __restrict__ out) {
    int l = blockIdx.x * 256 + threadIdx.x;
    int ch = blockIdx.y, b = blockIdx.z;
    int y = l >> 6, x = l & 63;
    const float* src = in + ((size_t)(b * 192 + ch)) * 4096;
    const float* wk = w + ch * 9;
    float acc = 0.f;
    #pragma unroll
    for (int ky = 0; ky < 3; ++ky)
        #pragma unroll
        for (int kx = 0; kx < 3; ++kx) {
            int yy = y + ky - 1, xx = x + kx - 1;
            if (yy >= 0 && yy < 64 && xx >= 0 && xx < 64)
                acc += wk[ky * 3 + kx] * src[yy * 64 + xx];
        }
    out[((size_t)(b * 192 + ch)) * 4096 + l] = acc;
}

// Final attention logits+softmax, one block per q-row. grid (768), 256 thr.
__global__ void attnF_row_kernel(const float* __restrict__ qn, const float* __restrict__ kn,
                                 const float* __restrict__ temp, float* __restrict__ AF) {
    int row = blockIdx.x;            // ((b*6+hh)*32 + c)
    int hh = (row >> 5) % 6, b = row / 192;
    int tid = threadIdx.x;
    const float* q = qn + ((size_t)(b * 192) + (row % 192)) * 4096;
    const float* kb = kn + ((size_t)(b * 192 + hh * 32)) * 4096;
    float acc[32];
    #pragma unroll
    for (int d = 0; d < 32; ++d) acc[d] = 0.f;
    for (int i = tid; i < 4096; i += 256) {
        float qv = q[i];
        #pragma unroll
        for (int d = 0; d < 32; ++d) acc[d] += qv * kb[(size_t)d * 4096 + i];
    }
    #pragma unroll
    for (int d = 0; d < 32; ++d) {
        acc[d] += __shfl_xor(acc[d], 32);
        acc[d] += __shfl_xor(acc[d], 16);
        acc[d] += __shfl_xor(acc[d], 8);
        acc[d] += __shfl_xor(acc[d], 4);
        acc[d] += __shfl_xor(acc[d], 2);
        acc[d] += __shfl_xor(acc[d], 1);
    }
    __shared__ float red[4][32];
    int wid = tid >> 6, lane = tid & 63;
    if (lane == 0) {
        #pragma unroll
        for (int d = 0; d < 32; ++d) red[wid][d] = acc[d];
    }
    __syncthreads();
    if (tid < 32) {
        float s = red[0][tid] + red[1][tid] + red[2][tid] + red[3][tid];
        s *= temp[hh];
        float mx = s;
        mx = fmaxf(mx, __shfl_xor(mx, 16));
        mx = fmaxf(mx, __shfl_xor(mx, 8));
        mx = fmaxf(mx, __shfl_xor(mx, 4));
        mx = fmaxf(mx, __shfl_xor(mx, 2));
        mx = fmaxf(mx, __shfl_xor(mx, 1));
        float e = expf(s - mx);
        float sum = e;
        sum += __shfl_xor(sum, 16);
        sum += __shfl_xor(sum, 8);
        sum += __shfl_xor(sum, 4);
        sum += __shfl_xor(sum, 2);
        sum += __shfl_xor(sum, 1);
        AF[(size_t)row * 32 + tid] = e / sum;
    }
}

__global__ void attnF_out_kernel(const float* __restrict__ AF, const float* __restrict__ v,
                                 float* __restrict__ out) {
    int l = blockIdx.x * 256 + threadIdx.x;
    int ch = blockIdx.y, b = blockIdx.z;
    int hh = ch >> 5, c = ch & 31;
    const float* a = AF + ((size_t)((b * 6 + hh) * 32 + c)) * 32;
    const float* vp = v + ((size_t)(b * 192 + hh * 32)) * 4096 + l;
    float acc = 0.f;
    #pragma unroll
    for (int d = 0; d < 32; ++d) acc += a[d] * vp[(size_t)d * 4096];
    out[((size_t)(b * 192 + ch)) * 4096 + l] = acc;
}

// ---------------- launch ----------------
extern "C" void kernel_launch(void* const* d_in, const int* in_sizes, int n_in,
                              void* d_out, int out_size, void* d_ws, size_t ws_size,
                              hipStream_t stream) {
    const float* I    = (const float*)d_in[0];
    const float* T    = (const float*)d_in[1];
    const float* temp = (const float*)d_in[2];
    const float* ca1  = (const float*)d_in[3];
    const float* exow = (const float*)d_in[4];
    const float* exob = (const float*)d_in[5];
    const float* kvw  = (const float*)d_in[6];
    const float* kvdw = (const float*)d_in[7];
    const float* qdw  = (const float*)d_in[8];
    const float* projw= (const float*)d_in[9];
    ExPtrs ep;
    for (int j = 0; j < 12; ++j) {
        ep.w[j] = (const float*)d_in[10 + 2 * j];
        ep.b[j] = (const float*)d_in[11 + 2 * j];
    }

    // Arena (floats), ~63 MB:
    float* ws   = (float*)d_ws;
    float* AF   = ws;                       // 24576
    int*   idxb = (int*)(ws + 24576);       // 4
    float* R0   = ws + 32768;               // 3,145,728
    float* R1   = R0 + 3145728;             // 3,145,728
    float* IbfF = R1 + 3145728;             // 3,551,232 floats region (Ibf bf16; later KN)
    float* EbfF = IbfF + 3551232;           // 3,446,784 floats (Ebf bf16; later V)
    double* dsm = (double*)(EbfF + 3446784);
    double* A64 = dsm;                      // 1536
    double* m64 = dsm + 1536;               // 64
    double* PA  = dsm + 1600;               // 24576
    double* kcol = dsm + 26176;             // 3072
    double* wsum = dsm + 29248;             // 192
    float* wtkv   = (float*)(dsm + 29440);  // 73,728
    float* wtproj = wtkv + 73728;           // 36,864
    float* wdwt   = wtproj + 36864;         // 28,800 (dw transposed weights)
    short* At     = (short*)(wdwt + 28800);     // exout pack: 1,327,104 shorts
    short* Adt    = At + 1327104;               // dense packs: 2,580,480 shorts
    size_t adtoff[6] = {0, 36864, 368640, 1290240, 1327104, 1658880};
    double* xpool64 = (double*)R0;               // 196,608 d
    double* qn64    = (double*)(R0 + 393216);    // 786,432 d
    short* Ibf = (short*)IbfF;
    short* Ebf = (short*)EbfF;
    float* KN = IbfF;
    float* V  = EbfF;
    BfPtrs bp;
    for (int j = 0; j < 6; ++j) { bp.adt[j] = Adt + adtoff[j]; bp.bias[j] = ep.b[j]; }
    float* out  = (float*)d_out;

    dim3 g(16, 192, 4), gs8(4, 24, 4), gmf(64, 2, 4), gdw(1024, 4);

    // ---- packs ----
    for (int j = 0; j < 6; ++j) {
        int KK = 1 + 2 * (j % 3);
        packAd_kernel<<<512, 256, 0, stream>>>(ep.w[j], Adt + adtoff[j], KK * KK);
    }
    packA_kernel<<<1024, 256, 0, stream>>>(exow, At);
    wtr8_kernel<<<256, 256, 0, stream>>>(kvw, wtkv, 48, 192, 1);
    wtr8_kernel<<<256, 256, 0, stream>>>(projw, wtproj, 24, 192, 1);
    packWdw_kernel<<<113, 256, 0, stream>>>(ep, wdwt);
    packIbf_kernel<<<2048, 256, 0, stream>>>(I, Ibf);

    // ---- Routing chain (b=0, f64, linearity-collapsed tail) ----
    pool64_kernel<<<48, 256, 0, stream>>>(T, xpool64);
    norm64_f32_kernel<<<192, 256, 0, stream>>>(I, qn64);
    norm64_f64_kernel<<<48, 256, 0, stream>>>(xpool64);
    attnA64p_kernel<<<dim3(6, 16), 256, 0, stream>>>(qn64, xpool64, PA);
    attnA64r_kernel<<<6, 256, 0, stream>>>(PA, A64);
    kcol64_kernel<<<48, 64, 0, stream>>>(xpool64, kcol);
    wsum64_kernel<<<1, 192, 0, stream>>>(ca1, wsum);
    mroute64_kernel<<<1, 64, 0, stream>>>(A64, kcol, wsum, m64);
    route64_kernel<<<1, 64, 0, stream>>>(m64, idxb);

    // ---- Experts: MFMA dense + coalesced dw -> Ebf bf16; exout MFMA -> R1 ----
    zero_kernel<<<2048, 256, 0, stream>>>(EbfF, 3446784);
    for (int s = 0; s < 4; ++s) {
        dense_mfma_kernel<<<gmf, 192, 0, stream>>>(bp, Ibf, idxb, s, Ebf, s & 1);
        dw_bf_kernel<<<gdw, 192, 0, stream>>>(Ibf, wdwt, ep, idxb, s, Ebf, s & 1);
        if (s == 1)
            exout_mfma_kernel<<<gmf, 192, 0, stream>>>(At, Ebf, exob, R1, 0);
        if (s == 3)
            exout_mfma_kernel<<<gmf, 192, 0, stream>>>(At, Ebf, exob, R1, 1);
    }

    // ---- kv k-half (Ibf dead -> KN) ----
    conv1x1_sw_kernel<<<gs8, 256, 0, stream>>>(R1, wtkv, R0);
    dwconv_kernel<<<g, 256, 0, stream>>>(R0, kvdw, KN);
    rownorm_kernel<<<768, 256, 0, stream>>>(KN, KN);             // kn
    // ---- q ----
    dwconv_kernel<<<g, 256, 0, stream>>>(R1, qdw, R0);
    rownorm_kernel<<<768, 256, 0, stream>>>(R0, R0);             // qn
    attnF_row_kernel<<<768, 256, 0, stream>>>(R0, KN, temp, AF);
    // ---- kv v-half (Ebf dead -> V) ----
    conv1x1_sw_kernel<<<gs8, 256, 0, stream>>>(R1, wtkv + 36864, R0);
    dwconv_kernel<<<g, 256, 0, stream>>>(R0, kvdw + 192 * 9, V);

    attnF_out_kernel<<<g, 256, 0, stream>>>(AF, V, R0);
    conv1x1_sw_kernel<<<gs8, 256, 0, stream>>>(R0, wtproj, out);
}

// Round 26
// 503.520 us; speedup vs baseline: 1.2365x; 1.2365x over previous
//
#include <hip/hip_runtime.h>
#include <math.h>

// B=4, DIM=192, H=W=64, L=4096, HEADS=6. f32 buffers; f64 routing chain (b=0).
// Dense experts AND ex_out via bf16 MFMA 16x16x32 GEMM-conv with LDS-staged rows.
// One 12-wave block per (y,b): row staged ONCE (was 3x in r22), mt = wave.
// Depthwise expert: ch-coalesced, transposed weights in registers, 4 px/block.
// Routing tail collapsed by linearity (exact in f64).

struct ExPtrs { const float* w[12]; const float* b[12]; };
struct BfPtrs { const short* adt[6]; const float* bias[6]; };

typedef __attribute__((ext_vector_type(8))) short short8v;
typedef __attribute__((ext_vector_type(4))) short short4v;
typedef __attribute__((ext_vector_type(4))) float f32x4;

__device__ __forceinline__ void fma4(float4& a, float s, const float4& v) {
    a.x = fmaf(s, v.x, a.x); a.y = fmaf(s, v.y, a.y);
    a.z = fmaf(s, v.z, a.z); a.w = fmaf(s, v.w, a.w);
}

__device__ __forceinline__ short f2bf(float v) {
    unsigned u = __float_as_uint(v);
    return (short)((u + 0x7FFFu + ((u >> 16) & 1u)) >> 16);
}

__device__ __forceinline__ float bf2f(short v) {
    return __uint_as_float(((unsigned)(unsigned short)v) << 16);
}

// ---------------- helpers ----------------
__global__ void zero_kernel(float* __restrict__ p, int n) {
    for (int i = blockIdx.x * 256 + threadIdx.x; i < n; i += gridDim.x * 256) p[i] = 0.f;
}

__global__ void packIbf_kernel(const float* __restrict__ I, short* __restrict__ Ibf) {
    const int n = 4 * 68 * 68 * 192;
    for (int o = blockIdx.x * 256 + threadIdx.x; o < n; o += gridDim.x * 256) {
        int ch = o % 192;
        int t = o / 192;
        int xx = t % 68; t /= 68;
        int yy = t % 68;
        int b = t / 68;
        short v = 0;
        if (yy >= 2 && yy < 66 && xx >= 2 && xx < 66)
            v = f2bf(I[(((size_t)(b * 192 + ch)) << 12) + (yy - 2) * 64 + (xx - 2)]);
        Ibf[o] = v;
    }
}

// dense expert j weights [192][192][K][K] -> bf16 [tap][mt(12)][ksg(6)][lane(64)][8]
__global__ void packAd_kernel(const float* __restrict__ w, short* __restrict__ Ad, int K2) {
    int n = K2 * 12 * 6 * 64 * 8;
    for (int o = blockIdx.x * 256 + threadIdx.x; o < n; o += gridDim.x * 256) {
        int u = o & 7;
        int t = o >> 3;
        int l = t & 63; t >>= 6;
        int ksg = t % 6; t /= 6;
        int mt = t % 12;
        int tap = t / 12;
        int oc = mt * 16 + (l & 15);
        int ic = ksg * 32 + (l >> 4) * 8 + u;
        Ad[o] = f2bf(w[(((size_t)oc * 192) + ic) * K2 + tap]);
    }
}

// exow [192][768][3][3] -> At bf16 [tap][mt(12)][ksg(24)][lane(64)][8]
__global__ void packA_kernel(const float* __restrict__ exow, short* __restrict__ At) {
    const int n = 9 * 12 * 24 * 64 * 8;
    for (int o = blockIdx.x * 256 + threadIdx.x; o < n; o += gridDim.x * 256) {
        int j = o & 7;
        int t = o >> 3;
        int l = t & 63; t >>= 6;
        int ksg = t % 24; t /= 24;
        int mt = t % 12;
        int tap = t / 12;
        int oc = mt * 16 + (l & 15);
        int icg = ksg * 32 + (l >> 4) * 8 + j;
        At[o] = f2bf(exow[((size_t)oc * 768 + icg) * 9 + tap]);
    }
}

__global__ void wtr8_kernel(const float* __restrict__ w, float* __restrict__ wt,
                            int OCg, int IC, int K2) {
    int n = OCg * IC * K2 * 8;
    for (int o = blockIdx.x * 256 + threadIdx.x; o < n; o += gridDim.x * 256) {
        int u = o & 7;
        int t = o >> 3;
        int kk = t % K2;
        int t2 = t / K2;
        int ic = t2 % IC;
        int og = t2 / IC;
        wt[o] = w[(((size_t)(og * 8 + u)) * IC + ic) * K2 + kk];
    }
}

// dw experts (j=6..11): wdwt[e][kk][ch] = w_j[ch*K2+kk]. 6*25*192 entries.
__global__ void packWdw_kernel(ExPtrs ep, float* __restrict__ wdwt) {
    int o = blockIdx.x * 256 + threadIdx.x;
    if (o >= 6 * 25 * 192) return;
    int ch = o % 192;
    int t = o / 192;
    int kk = t % 25;
    int e = t / 25;
    int j = e + 6;
    int K = 1 + 2 * (j % 3);
    int K2 = K * K;
    wdwt[o] = (kk < K2) ? ep.w[j][(size_t)ch * K2 + kk] : 0.f;
}

// ================= routing chain, b=0, all f64 =================

__global__ void pool64_kernel(const float* __restrict__ T, double* __restrict__ xp) {
    int j = blockIdx.x;
    for (int l = threadIdx.x; l < 4096; l += 256) {
        const float* t = T + ((size_t)(4 * j)) * 4096 + l;
        double s = (double)t[0] + (double)t[4096] + (double)t[2 * 4096] + (double)t[3 * 4096];
        xp[(size_t)j * 4096 + l] = 0.25 * s;
    }
}

__global__ void norm64_f32_kernel(const float* __restrict__ src, double* __restrict__ dst) {
    size_t off = (size_t)blockIdx.x * 4096;
    double acc = 0.0;
    for (int i = threadIdx.x; i < 4096; i += 256) { double v = src[off + i]; acc += v * v; }
    __shared__ double red[256];
    red[threadIdx.x] = acc; __syncthreads();
    for (int st = 128; st > 0; st >>= 1) {
        if (threadIdx.x < st) red[threadIdx.x] += red[threadIdx.x + st];
        __syncthreads();
    }
    double scale = 1.0 / fmax(sqrt(red[0]), 1e-12);
    for (int i = threadIdx.x; i < 4096; i += 256) dst[off + i] = src[off + i] * scale;
}

__global__ void norm64_f64_kernel(double* __restrict__ buf) {
    size_t off = (size_t)blockIdx.x * 4096;
    double acc = 0.0;
    for (int i = threadIdx.x; i < 4096; i += 256) { double v = buf[off + i]; acc += v * v; }
    __shared__ double red[256];
    red[threadIdx.x] = acc; __syncthreads();
    for (int st = 128; st > 0; st >>= 1) {
        if (threadIdx.x < st) red[threadIdx.x] += red[threadIdx.x + st];
        __syncthreads();
    }
    double scale = 1.0 / fmax(sqrt(red[0]), 1e-12);
    for (int i = threadIdx.x; i < 4096; i += 256) buf[off + i] *= scale;
}

__global__ void attnA64p_kernel(const double* __restrict__ qn, const double* __restrict__ kn,
                                double* __restrict__ PA) {
    int hh = blockIdx.x, cc = blockIdx.y;
    int t = threadIdx.x;
    int c = t >> 3, d = t & 7;
    const double* q = qn + ((size_t)(hh * 32 + c)) * 4096 + cc * 256;
    const double* k = kn + ((size_t)(hh * 8 + d)) * 4096 + cc * 256;
    double acc = 0.0;
    for (int i = 0; i < 256; ++i) acc += q[i] * k[i];
    PA[((size_t)((hh * 32 + c) * 8 + d)) * 16 + cc] = acc;
}

__global__ void attnA64r_kernel(const double* __restrict__ PA, double* __restrict__ A) {
    int hh = blockIdx.x;
    int t = threadIdx.x;
    int c = t >> 3, d = t & 7;
    double acc = 0.0;
    const double* p = PA + ((size_t)((hh * 32 + c) * 8 + d)) * 16;
    for (int cc = 0; cc < 16; ++cc) acc += p[cc];
    __shared__ double S[32][8];
    S[c][d] = acc;
    __syncthreads();
    if (t < 32) {
        double mx = -1e300;
        for (int j = 0; j < 8; ++j) mx = fmax(mx, S[t][j]);
        double e[8], sum = 0.0;
        for (int j = 0; j < 8; ++j) { e[j] = exp(S[t][j] - mx); sum += e[j]; }
        double inv = 1.0 / sum;
        for (int j = 0; j < 8; ++j) A[((size_t)(hh * 32 + t)) * 8 + j] = e[j] * inv;
    }
}

// kcol[j][x] = sum_y kn[j][y*64+x], j<48. grid (48), 64 thr.
__global__ void kcol64_kernel(const double* __restrict__ kn, double* __restrict__ kcol) {
    int j = blockIdx.x, x = threadIdx.x;
    const double* s = kn + (size_t)j * 4096 + x;
    double acc = 0.0;
    for (int y = 0; y < 64; ++y) acc += s[y * 64];
    kcol[j * 64 + x] = acc;
}

// wsum[ic] = sum_oc ca1[oc*192+ic]. grid (1), 192 thr.
__global__ void wsum64_kernel(const float* __restrict__ ca1, double* __restrict__ wsum) {
    int ic = threadIdx.x;
    if (ic >= 192) return;
    double acc = 0.0;
    for (int oc = 0; oc < 192; ++oc) acc += (double)ca1[(size_t)oc * 192 + ic];
    wsum[ic] = acc;
}

// m[x] = (1/12288) sum_ic wsum[ic] * sum_d A[ic*8+d]*kcol[(ic>>5)*8+d][x]. grid (1), 64 thr.
__global__ void mroute64_kernel(const double* __restrict__ A, const double* __restrict__ kcol,
                                const double* __restrict__ wsum, double* __restrict__ m) {
    int x = threadIdx.x;
    if (x >= 64) return;
    double acc = 0.0;
    for (int ic = 0; ic < 192; ++ic) {
        int hh = ic >> 5;
        double s = 0.0;
        #pragma unroll
        for (int d = 0; d < 8; ++d)
            s += A[(size_t)ic * 8 + d] * kcol[(hh * 8 + d) * 64 + x];
        acc += wsum[ic] * s;
    }
    m[x] = acc / (192.0 * 64.0);
}

__global__ void route64_kernel(const double* __restrict__ m, int* __restrict__ idx) {
    if (threadIdx.x != 0) return;
    double bins[12];
    for (int i = 0; i < 12; ++i) {
        int st = (i * 64) / 12;
        int en = ((i + 1) * 64 + 11) / 12;   // ceil
        double s = 0.0;
        for (int j = st; j < en; ++j) s += m[j];
        bins[i] = s / (double)(en - st);
    }
    bool used[12] = {};
    for (int s = 0; s < 4; ++s) {
        int best = 0; double bv = -1e300;
        for (int j = 0; j < 12; ++j)
            if (!used[j] && bins[j] > bv) { best = j; bv = bins[j]; }
        used[best] = true;
        idx[s] = best;
    }
}

// ================= f32 compute kernels =================

__global__ void rownorm_kernel(const float* __restrict__ src, float* __restrict__ dst) {
    size_t off = (size_t)blockIdx.x * 4096;
    const float* s = src + off;
    float acc = 0.f;
    for (int i = threadIdx.x; i < 4096; i += 256) { float v = s[i]; acc += v * v; }
    __shared__ float red[256];
    red[threadIdx.x] = acc; __syncthreads();
    for (int st = 128; st > 0; st >>= 1) {
        if (threadIdx.x < st) red[threadIdx.x] += red[threadIdx.x + st];
        __syncthreads();
    }
    float scale = 1.0f / fmaxf(sqrtf(red[0]), 1e-12f);
    float* d = dst + off;
    for (int i = threadIdx.x; i < 4096; i += 256) d[i] = s[i] * scale;
}

// ---- dense expert via 16x16x32 MFMA with LDS-staged B rows. ----
// One 12-wave block per (y,b); mt = wave (0..11); row staged once.
template<int KK>
__device__ __forceinline__ void dmf_body(const short* __restrict__ Ad,
                                         const short* __restrict__ Ibf,
                                         const float* __restrict__ bias,
                                         short* __restrict__ Ebf, int cslot,
                                         int b, int y, short* __restrict__ sb) {
    constexpr int P = (KK - 1) / 2;
    int tid = threadIdx.x;
    int lane = tid & 63;
    int mt = tid >> 6;                      // wave 0..11 = mt
    int ln = lane & 15, kb = lane >> 4;
    f32x4 acc[4];
    #pragma unroll
    for (int c = 0; c < 4; ++c)
        #pragma unroll
        for (int r = 0; r < 4; ++r)
            acc[c][r] = bias[mt * 16 + kb * 4 + r];
    for (int rr = 0; rr < KK; ++rr) {
        const short* src = Ibf + ((size_t)(b * 68 + y + 2 - P + rr)) * 68 * 192;
        if (rr > 0) __syncthreads();
        for (int g2 = tid; g2 < 68 * 24; g2 += 768) {
            int px = g2 / 24, ck = g2 % 24;
            *(short8v*)(sb + px * 200 + ck * 8) = *(const short8v*)(src + px * 192 + ck * 8);
        }
        __syncthreads();
        for (int dx = 0; dx < KK; ++dx) {
            int tap = rr * KK + dx;
            const short* Ab = Ad + (((size_t)(tap * 12 + mt)) * 6 * 64 + lane) * 8;
            #pragma unroll
            for (int ks = 0; ks < 6; ++ks) {
                short8v av = *(const short8v*)(Ab + ks * 512);
                int kc = ks * 32 + kb * 8;
                #pragma unroll
                for (int c = 0; c < 4; ++c) {
                    short8v bv = *(const short8v*)(sb + ((2 - P) + dx + c * 16 + ln) * 200 + kc);
                    acc[c] = __builtin_amdgcn_mfma_f32_16x16x32_bf16(av, bv, acc[c], 0, 0, 0);
                }
            }
        }
    }
    #pragma unroll
    for (int c = 0; c < 4; ++c) {
        int x = c * 16 + ln;
        short* d = Ebf + (((size_t)(b * 66 + y + 1)) * 68 + (x + 1)) * 384 + cslot * 192 + mt * 16 + kb * 4;
        short4v o;
        #pragma unroll
        for (int r = 0; r < 4; ++r) o[r] = f2bf(acc[c][r]);
        *(short4v*)d = o;
    }
}

// grid (64, 1, 4), 768 thr.
__global__ void dense_mfma_kernel(BfPtrs bp, const short* __restrict__ Ibf,
                                  const int* __restrict__ idx, int slot,
                                  short* __restrict__ Ebf, int cslot) {
    __shared__ short sb[68 * 200];
    int j = idx[slot];
    j = j < 0 ? 0 : (j > 11 ? 11 : j);
    if (j >= 6) return;
    int y = blockIdx.x, b = blockIdx.z;
    int m = j % 3;
    if (m == 0) dmf_body<1>(bp.adt[j], Ibf, bp.bias[j], Ebf, cslot, b, y, sb);
    else if (m == 1) dmf_body<3>(bp.adt[j], Ibf, bp.bias[j], Ebf, cslot, b, y, sb);
    else dmf_body<5>(bp.adt[j], Ibf, bp.bias[j], Ebf, cslot, b, y, sb);
}

// ---- depthwise body: ch-coalesced, weights in registers, 4 px/block ----
template<int KK>
__device__ __forceinline__ void dw_body(const short* __restrict__ Ibf,
                                        const float* __restrict__ wt,
                                        float bias,
                                        short* __restrict__ Ebf, int cslot,
                                        int b, int pg, int ch) {
    constexpr int P = (KK - 1) / 2;
    constexpr int K2 = KK * KK;
    float wreg[K2];
    #pragma unroll
    for (int kk = 0; kk < K2; ++kk) wreg[kk] = wt[kk * 192 + ch];
    #pragma unroll
    for (int u = 0; u < 4; ++u) {
        int px = pg * 4 + u;
        int y = px >> 6, x = px & 63;
        const short* base = Ibf + ((size_t)(b * 68 + y + 2 - P)) * 68 * 192
                            + (size_t)(x + 2 - P) * 192 + ch;
        float acc = bias;
        #pragma unroll
        for (int ky = 0; ky < KK; ++ky)
            #pragma unroll
            for (int kx = 0; kx < KK; ++kx)
                acc = fmaf(wreg[ky * KK + kx], bf2f(base[(ky * 68 + kx) * 192]), acc);
        Ebf[(((size_t)(b * 66 + y + 1)) * 68 + (x + 1)) * 384 + cslot * 192 + ch] = f2bf(acc);
    }
}

// grid (1024, 4), 192 thr.
__global__ void dw_bf_kernel(const short* __restrict__ Ibf, const float* __restrict__ wdwt,
                             ExPtrs ep, const int* __restrict__ idx, int slot,
                             short* __restrict__ Ebf, int cslot) {
    int j = idx[slot];
    j = j < 0 ? 0 : (j > 11 ? 11 : j);
    if (j < 6) return;
    int ch = threadIdx.x;
    int pg = blockIdx.x, b = blockIdx.y;
    const float* wt = wdwt + (size_t)(j - 6) * 25 * 192;
    float bias = ep.b[j][ch];
    int m = j % 3;
    if (m == 0) dw_body<1>(Ibf, wt, bias, Ebf, cslot, b, pg, ch);
    else if (m == 1) dw_body<3>(Ibf, wt, bias, Ebf, cslot, b, pg, ch);
    else dw_body<5>(Ibf, wt, bias, Ebf, cslot, b, pg, ch);
}

// ex_out via 16x16x32 MFMA with LDS-staged B rows. grid (64,1,4), 768 thr.
__global__ void exout_mfma_kernel(const short* __restrict__ At, const short* __restrict__ Ebf,
                                  const float* __restrict__ bias, float* __restrict__ out,
                                  int pass) {
    __shared__ short sb[68 * 392];
    int y = blockIdx.x, b = blockIdx.z;
    int tid = threadIdx.x;
    int lane = tid & 63;
    int mt = tid >> 6;                      // wave 0..11 = mt
    int ln = lane & 15, kb = lane >> 4;
    float* dst = out + ((size_t)(b * 192 + mt * 16)) * 4096 + y * 64;
    f32x4 acc[4];
    if (pass == 0) {
        #pragma unroll
        for (int c = 0; c < 4; ++c)
            #pragma unroll
            for (int r = 0; r < 4; ++r)
                acc[c][r] = bias[mt * 16 + kb * 4 + r];
    } else {
        #pragma unroll
        for (int c = 0; c < 4; ++c)
            #pragma unroll
            for (int r = 0; r < 4; ++r)
                acc[c][r] = dst[(size_t)(kb * 4 + r) * 4096 + c * 16 + ln];
    }
    for (int rr = 0; rr < 3; ++rr) {
        const short* src = Ebf + ((size_t)(b * 66 + y + rr)) * 68 * 384;
        if (rr > 0) __syncthreads();
        for (int g2 = tid; g2 < 68 * 48; g2 += 768) {
            int px = g2 / 48, ck = g2 % 48;
            *(short8v*)(sb + px * 392 + ck * 8) = *(const short8v*)(src + px * 384 + ck * 8);
        }
        __syncthreads();
        for (int dx = 0; dx < 3; ++dx) {
            int tap = rr * 3 + dx;
            const short* Ab = At + (((size_t)((tap * 12 + mt) * 24) + pass * 12) * 64 + lane) * 8;
            #pragma unroll
            for (int ks = 0; ks < 12; ++ks) {
                short8v av = *(const short8v*)(Ab + (size_t)ks * 512);
                int kc = ks * 32 + kb * 8;
                #pragma unroll
                for (int c = 0; c < 4; ++c) {
                    short8v bv = *(const short8v*)(sb + (dx + c * 16 + ln) * 392 + kc);
                    acc[c] = __builtin_amdgcn_mfma_f32_16x16x32_bf16(av, bv, acc[c], 0, 0, 0);
                }
            }
        }
    }
    #pragma unroll
    for (int c = 0; c < 4; ++c)
        #pragma unroll
        for (int r = 0; r < 4; ++r)
            dst[(size_t)(kb * 4 + r) * 4096 + c * 16 + ln] = acc[c][r];
}

// 1x1 conv, 8oc. grid (4, 24, 4). wt pre-offset for oc-half.
__global__ void conv1x1_sw_kernel(const float* __restrict__ in, const float* __restrict__ wtg,
                                  float* __restrict__ out) {
    int tid = threadIdx.x;
    int xq = tid & 15, ry = tid >> 4;
    int tile = blockIdx.x, og = blockIdx.y, b = blockIdx.z;
    int p0 = tile * 1024 + ry * 64 + xq * 4;
    float4 acc[8] = {};
    const float* src = in + (size_t)b * 192 * 4096 + p0;
    const float* wp = wtg + (size_t)og * 192 * 8;
    for (int ic = 0; ic < 192; ic += 2) {
        float4 xv0 = *(const float4*)(src + (size_t)ic * 4096);
        float4 xv1 = *(const float4*)(src + (size_t)(ic + 1) * 4096);
        float4 wA0 = *(const float4*)(wp + ic * 8);
        float4 wB0 = *(const float4*)(wp + ic * 8 + 4);
        float4 wA1 = *(const float4*)(wp + ic * 8 + 8);
        float4 wB1 = *(const float4*)(wp + ic * 8 + 12);
        fma4(acc[0], wA0.x, xv0); fma4(acc[1], wA0.y, xv0);
        fma4(acc[2], wA0.z, xv0); fma4(acc[3], wA0.w, xv0);
        fma4(acc[4], wB0.x, xv0); fma4(acc[5], wB0.y, xv0);
        fma4(acc[6], wB0.z, xv0); fma4(acc[7], wB0.w, xv0);
        fma4(acc[0], wA1.x, xv1); fma4(acc[1], wA1.y, xv1);
        fma4(acc[2], wA1.z, xv1); fma4(acc[3], wA1.w, xv1);
        fma4(acc[4], wB1.x, xv1); fma4(acc[5], wB1.y, xv1);
        fma4(acc[6], wB1.z, xv1); fma4(acc[7], wB1.w, xv1);
    }
    float* dst = out + ((size_t)(b * 192 + og * 8)) * 4096 + p0;
    #pragma unroll
    for (int u = 0; u < 8; ++u)
        *(float4*)(dst + (size_t)u * 4096) = acc[u];
}

// depthwise 3x3 pad1 no bias; plain in/out; w pre-offset. grid (16,192,4)
__global__ void dwconv_kernel(const float* __restrict__ in, const float* __restrict__ w,
                              float* __restrict__ out) {
    int l = blockIdx.x * 256 + threadIdx.x;
    int ch = blockIdx.y, b = blockIdx.z;
    int y = l >> 6, x = l & 63;
    const float* src = in + ((size_t)(b * 192 + ch)) * 4096;
    const float* wk = w + ch * 9;
    float acc = 0.f;
    #pragma unroll
    for (int ky = 0; ky < 3; ++ky)
        #pragma unroll
        for (int kx = 0; kx < 3; ++kx) {
            int yy = y + ky - 1, xx = x + kx - 1;
            if (yy >= 0 && yy < 64 && xx >= 0 && xx < 64)
                acc += wk[ky * 3 + kx] * src[yy * 64 + xx];
        }
    out[((size_t)(b * 192 + ch)) * 4096 + l] = acc;
}

// Final attention logits+softmax, one block per q-row. grid (768), 256 thr.
__global__ void attnF_row_kernel(const float* __restrict__ qn, const float* __restrict__ kn,
                                 const float* __restrict__ temp, float* __restrict__ AF) {
    int row = blockIdx.x;            // ((b*6+hh)*32 + c)
    int hh = (row >> 5) % 6, b = row / 192;
    int tid = threadIdx.x;
    const float* q = qn + ((size_t)(b * 192) + (row % 192)) * 4096;
    const float* kb = kn + ((size_t)(b * 192 + hh * 32)) * 4096;
    float acc[32];
    #pragma unroll
    for (int d = 0; d < 32; ++d) acc[d] = 0.f;
    for (int i = tid; i < 4096; i += 256) {
        float qv = q[i];
        #pragma unroll
        for (int d = 0; d < 32; ++d) acc[d] += qv * kb[(size_t)d * 4096 + i];
    }
    #pragma unroll
    for (int d = 0; d < 32; ++d) {
        acc[d] += __shfl_xor(acc[d], 32);
        acc[d] += __shfl_xor(acc[d], 16);
        acc[d] += __shfl_xor(acc[d], 8);
        acc[d] += __shfl_xor(acc[d], 4);
        acc[d] += __shfl_xor(acc[d], 2);
        acc[d] += __shfl_xor(acc[d], 1);
    }
    __shared__ float red[4][32];
    int wid = tid >> 6, lane = tid & 63;
    if (lane == 0) {
        #pragma unroll
        for (int d = 0; d < 32; ++d) red[wid][d] = acc[d];
    }
    __syncthreads();
    if (tid < 32) {
        float s = red[0][tid] + red[1][tid] + red[2][tid] + red[3][tid];
        s *= temp[hh];
        float mx = s;
        mx = fmaxf(mx, __shfl_xor(mx, 16));
        mx = fmaxf(mx, __shfl_xor(mx, 8));
        mx = fmaxf(mx, __shfl_xor(mx, 4));
        mx = fmaxf(mx, __shfl_xor(mx, 2));
        mx = fmaxf(mx, __shfl_xor(mx, 1));
        float e = expf(s - mx);
        float sum = e;
        sum += __shfl_xor(sum, 16);
        sum += __shfl_xor(sum, 8);
        sum += __shfl_xor(sum, 4);
        sum += __shfl_xor(sum, 2);
        sum += __shfl_xor(sum, 1);
        AF[(size_t)row * 32 + tid] = e / sum;
    }
}

__global__ void attnF_out_kernel(const float* __restrict__ AF, const float* __restrict__ v,
                                 float* __restrict__ out) {
    int l = blockIdx.x * 256 + threadIdx.x;
    int ch = blockIdx.y, b = blockIdx.z;
    int hh = ch >> 5, c = ch & 31;
    const float* a = AF + ((size_t)((b * 6 + hh) * 32 + c)) * 32;
    const float* vp = v + ((size_t)(b * 192 + hh * 32)) * 4096 + l;
    float acc = 0.f;
    #pragma unroll
    for (int d = 0; d < 32; ++d) acc += a[d] * vp[(size_t)d * 4096];
    out[((size_t)(b * 192 + ch)) * 4096 + l] = acc;
}

// ---------------- launch ----------------
extern "C" void kernel_launch(void* const* d_in, const int* in_sizes, int n_in,
                              void* d_out, int out_size, void* d_ws, size_t ws_size,
                              hipStream_t stream) {
    const float* I    = (const float*)d_in[0];
    const float* T    = (const float*)d_in[1];
    const float* temp = (const float*)d_in[2];
    const float* ca1  = (const float*)d_in[3];
    const float* exow = (const float*)d_in[4];
    const float* exob = (const float*)d_in[5];
    const float* kvw  = (const float*)d_in[6];
    const float* kvdw = (const float*)d_in[7];
    const float* qdw  = (const float*)d_in[8];
    const float* projw= (const float*)d_in[9];
    ExPtrs ep;
    for (int j = 0; j < 12; ++j) {
        ep.w[j] = (const float*)d_in[10 + 2 * j];
        ep.b[j] = (const float*)d_in[11 + 2 * j];
    }

    // Arena (floats), ~63 MB:
    float* ws   = (float*)d_ws;
    float* AF   = ws;                       // 24576
    int*   idxb = (int*)(ws + 24576);       // 4
    float* R0   = ws + 32768;               // 3,145,728
    float* R1   = R0 + 3145728;             // 3,145,728
    float* IbfF = R1 + 3145728;             // 3,551,232 floats region (Ibf bf16; later KN)
    float* EbfF = IbfF + 3551232;           // 3,446,784 floats (Ebf bf16; later V)
    double* dsm = (double*)(EbfF + 3446784);
    double* A64 = dsm;                      // 1536
    double* m64 = dsm + 1536;               // 64
    double* PA  = dsm + 1600;               // 24576
    double* kcol = dsm + 26176;             // 3072
    double* wsum = dsm + 29248;             // 192
    float* wtkv   = (float*)(dsm + 29440);  // 73,728
    float* wtproj = wtkv + 73728;           // 36,864
    float* wdwt   = wtproj + 36864;         // 28,800 (dw transposed weights)
    short* At     = (short*)(wdwt + 28800);     // exout pack: 1,327,104 shorts
    short* Adt    = At + 1327104;               // dense packs: 2,580,480 shorts
    size_t adtoff[6] = {0, 36864, 368640, 1290240, 1327104, 1658880};
    double* xpool64 = (double*)R0;               // 196,608 d
    double* qn64    = (double*)(R0 + 393216);    // 786,432 d
    short* Ibf = (short*)IbfF;
    short* Ebf = (short*)EbfF;
    float* KN = IbfF;
    float* V  = EbfF;
    BfPtrs bp;
    for (int j = 0; j < 6; ++j) { bp.adt[j] = Adt + adtoff[j]; bp.bias[j] = ep.b[j]; }
    float* out  = (float*)d_out;

    dim3 g(16, 192, 4), gs8(4, 24, 4), gmf(64, 1, 4), gdw(1024, 4);

    // ---- packs ----
    for (int j = 0; j < 6; ++j) {
        int KK = 1 + 2 * (j % 3);
        packAd_kernel<<<512, 256, 0, stream>>>(ep.w[j], Adt + adtoff[j], KK * KK);
    }
    packA_kernel<<<1024, 256, 0, stream>>>(exow, At);
    wtr8_kernel<<<256, 256, 0, stream>>>(kvw, wtkv, 48, 192, 1);
    wtr8_kernel<<<256, 256, 0, stream>>>(projw, wtproj, 24, 192, 1);
    packWdw_kernel<<<113, 256, 0, stream>>>(ep, wdwt);
    packIbf_kernel<<<2048, 256, 0, stream>>>(I, Ibf);

    // ---- Routing chain (b=0, f64, linearity-collapsed tail) ----
    pool64_kernel<<<48, 256, 0, stream>>>(T, xpool64);
    norm64_f32_kernel<<<192, 256, 0, stream>>>(I, qn64);
    norm64_f64_kernel<<<48, 256, 0, stream>>>(xpool64);
    attnA64p_kernel<<<dim3(6, 16), 256, 0, stream>>>(qn64, xpool64, PA);
    attnA64r_kernel<<<6, 256, 0, stream>>>(PA, A64);
    kcol64_kernel<<<48, 64, 0, stream>>>(xpool64, kcol);
    wsum64_kernel<<<1, 192, 0, stream>>>(ca1, wsum);
    mroute64_kernel<<<1, 64, 0, stream>>>(A64, kcol, wsum, m64);
    route64_kernel<<<1, 64, 0, stream>>>(m64, idxb);

    // ---- Experts: MFMA dense + coalesced dw -> Ebf bf16; exout MFMA -> R1 ----
    zero_kernel<<<2048, 256, 0, stream>>>(EbfF, 3446784);
    for (int s = 0; s < 4; ++s) {
        dense_mfma_kernel<<<gmf, 768, 0, stream>>>(bp, Ibf, idxb, s, Ebf, s & 1);
        dw_bf_kernel<<<gdw, 192, 0, stream>>>(Ibf, wdwt, ep, idxb, s, Ebf, s & 1);
        if (s == 1)
            exout_mfma_kernel<<<gmf, 768, 0, stream>>>(At, Ebf, exob, R1, 0);
        if (s == 3)
            exout_mfma_kernel<<<gmf, 768, 0, stream>>>(At, Ebf, exob, R1, 1);
    }

    // ---- kv k-half (Ibf dead -> KN) ----
    conv1x1_sw_kernel<<<gs8, 256, 0, stream>>>(R1, wtkv, R0);
    dwconv_kernel<<<g, 256, 0, stream>>>(R0, kvdw, KN);
    rownorm_kernel<<<768, 256, 0, stream>>>(KN, KN);             // kn
    // ---- q ----
    dwconv_kernel<<<g, 256, 0, stream>>>(R1, qdw, R0);
    rownorm_kernel<<<768, 256, 0, stream>>>(R0, R0);             // qn
    attnF_row_kernel<<<768, 256, 0, stream>>>(R0, KN, temp, AF);
    // ---- kv v-half (Ebf dead -> V) ----
    conv1x1_sw_kernel<<<gs8, 256, 0, stream>>>(R1, wtkv + 36864, R0);
    dwconv_kernel<<<g, 256, 0, stream>>>(R0, kvdw + 192 * 9, V);

    attnF_out_kernel<<<g, 256, 0, stream>>>(AF, V, R0);
    conv1x1_sw_kernel<<<gs8, 256, 0, stream>>>(R0, wtproj, out);
}